// Round 10
// baseline (1929.769 us; speedup 1.0000x reference)
//
#include <hip/hip_runtime.h>

#define T_DIM 2048
#define B_DIM 50
#define F_DIM 750
#define H_DIM 100
#define G4    400             // 4*H
#define M_DIM (T_DIM * B_DIM) // 102400
#define KPAD  768             // F padded to MFMA-friendly K

typedef __attribute__((ext_vector_type(8))) short short8v;  // 8 bf16
typedef __attribute__((ext_vector_type(4))) float f32x4;
typedef __attribute__((ext_vector_type(2))) float f32x2;

__device__ __forceinline__ float fast_rcp(float x) { return __builtin_amdgcn_rcpf(x); }
__device__ __forceinline__ float tanh_f(float x) {
    return 1.0f - 2.0f * fast_rcp(__expf(2.0f * x) + 1.0f);
}

__device__ __forceinline__ unsigned short f2bf_rne(float f) {
    unsigned int u = __float_as_uint(f);
    u = (u + 0x7FFFu + ((u >> 16) & 1u)) >> 16;
    return (unsigned short)u;
}
__device__ __forceinline__ float bf2f(unsigned short h) {
    return __uint_as_float(((unsigned int)h) << 16);
}

template <int CTRL>
__device__ __forceinline__ float qperm(float x) {
    return __int_as_float(__builtin_amdgcn_mov_dpp(__float_as_int(x), CTRL, 0xF, 0xF, false));
}

// asm barrier for the GEMM only (no register-residency needs there)
__device__ __forceinline__ void lgkm_barrier() {
    __builtin_amdgcn_sched_barrier(0);
    asm volatile("s_waitcnt lgkmcnt(0)\ns_barrier" ::: "memory");
    __builtin_amdgcn_sched_barrier(0);
}

// ---------------------------------------------------------------------------
// Kernel 0a: W_ih (400x750 fp32) -> W_hi/W_lo (400x768 bf16, k-padded 0). RNE.
// ---------------------------------------------------------------------------
__global__ __launch_bounds__(256) void wconv(
    const float* __restrict__ W,
    unsigned short* __restrict__ Whi,
    unsigned short* __restrict__ Wlo)
{
    int i = blockIdx.x * 256 + threadIdx.x;
    if (i >= G4 * KPAD) return;
    int g = i / KPAD, k = i - g * KPAD;
    float v = (k < F_DIM) ? W[g * F_DIM + k] : 0.f;
    unsigned short h = f2bf_rne(v);
    Whi[i] = h;
    Wlo[i] = f2bf_rne(v - bf2f(h));
}

// ---------------------------------------------------------------------------
// Kernel 0b: repack W_hh for the quarter-split scan.
//   Lane (j,q) gets 112 contiguous floats: gate g in [g*28, g*28+28),
//   entry r = Whh[(g*100+j)*100 + 25q + r] for r<25, 0 for pads.
// ---------------------------------------------------------------------------
__global__ __launch_bounds__(256) void whh_pack(
    const float* __restrict__ Whh,   // (400, 100)
    float* __restrict__ wpack)       // (400 lanes, 112)
{
    int i = blockIdx.x * 256 + threadIdx.x;
    if (i >= 400 * 112) return;
    int lane = i / 112, rem = i - lane * 112;
    int g = rem / 28, r = rem - g * 28;
    int j = lane >> 2, q = lane & 3;
    wpack[i] = (r < 25) ? Whh[(size_t)(g * H_DIM + j) * H_DIM + 25 * q + r] : 0.f;
}

// ---------------------------------------------------------------------------
// Kernel 1: xp = x @ W_ih^T + b via bf16 split MFMA.  M-tile 128, 8 waves.
//   (unchanged from rounds 7-9)
// ---------------------------------------------------------------------------
__global__ __launch_bounds__(512, 1) void xproj_mfma(
    const float* __restrict__ x,            // (M, 750)
    const unsigned short* __restrict__ Whi, // (400, 768) bf16
    const unsigned short* __restrict__ Wlo,
    const float* __restrict__ bih,
    const float* __restrict__ bhh,
    float* __restrict__ xp)                 // (M, 400)
{
    const int m0   = blockIdx.x * 128;
    const int tid  = threadIdx.x;
    const int lane = tid & 63;
    const int w    = tid >> 6;            // wave 0..7
    const int rb   = (w >> 2) * 64;       // row block 0 / 64
    const int wc   = w & 3;               // col wave 0..3
    const int fr   = lane & 15;
    const int fk   = (lane >> 4) * 8;

    __shared__ unsigned short Ahi[2][128][40];   // 20 KB
    __shared__ unsigned short Alo[2][128][40];   // 20 KB

    f32x4 acc[4][7];
    #pragma unroll
    for (int s = 0; s < 4; ++s)
        #pragma unroll
        for (int t = 0; t < 7; ++t)
            acc[s][t] = (f32x4){0.f, 0.f, 0.f, 0.f};

    float bias_t[7];
    #pragma unroll
    for (int tt = 0; tt < 7; ++tt) {
        const int nt = wc + 4 * tt;
        if (nt < 25) {
            const int n = nt * 16 + fr;
            bias_t[tt] = bih[n] + bhh[n];
        } else bias_t[tt] = 0.f;
    }

    const int sr = tid >> 2;          // row 0..127
    const int sc = (tid & 3) * 8;     // k-chunk 0/8/16/24
    const float* xrow = x + (size_t)(m0 + sr) * F_DIM;

    float f[8];

    #define STAGE_LOAD(KS)                                                     \
    {                                                                          \
        const int kg = (KS) * 32 + sc;                                         \
        _Pragma("unroll")                                                      \
        for (int i = 0; i < 8; i += 2) {                                       \
            if (kg + i + 1 < F_DIM) {                                          \
                float2 v = *reinterpret_cast<const float2*>(&xrow[kg + i]);    \
                f[i] = v.x; f[i + 1] = v.y;                                    \
            } else {                                                           \
                f[i]     = (kg + i < F_DIM) ? xrow[kg + i] : 0.f;              \
                f[i + 1] = 0.f;                                                \
            }                                                                  \
        }                                                                      \
    }

    #define STAGE_WRITE(NB)                                                    \
    {                                                                          \
        short8v vh, vl;                                                        \
        _Pragma("unroll")                                                      \
        for (int i = 0; i < 8; ++i) {                                          \
            unsigned int u = __float_as_uint(f[i]);                            \
            vh[i] = (short)(u >> 16);                                          \
            float r = f[i] - __uint_as_float(u & 0xffff0000u);                 \
            vl[i] = (short)(__float_as_uint(r) >> 16);                         \
        }                                                                      \
        *reinterpret_cast<short8v*>(&Ahi[NB][sr][sc]) = vh;                    \
        *reinterpret_cast<short8v*>(&Alo[NB][sr][sc]) = vl;                    \
    }

    STAGE_LOAD(0);
    STAGE_WRITE(0);
    lgkm_barrier();

    for (int s = 0; s < 24; ++s) {
        const int cur = s & 1;
        short8v ah[4], al[4];
        #pragma unroll
        for (int st = 0; st < 4; ++st) {
            ah[st] = *reinterpret_cast<const short8v*>(&Ahi[cur][rb + st * 16 + fr][fk]);
            al[st] = *reinterpret_cast<const short8v*>(&Alo[cur][rb + st * 16 + fr][fk]);
        }

        if (s < 23) STAGE_LOAD(s + 1);    // issue loads early; consume after MFMA

        const int kb = s * 32 + fk;
        #pragma unroll
        for (int tt = 0; tt < 7; ++tt) {
            const int nt = wc + 4 * tt;
            if (nt < 25) {
                const int n = nt * 16 + fr;
                const short8v bh = *reinterpret_cast<const short8v*>(&Whi[n * KPAD + kb]);
                const short8v bl = *reinterpret_cast<const short8v*>(&Wlo[n * KPAD + kb]);
                #pragma unroll
                for (int st = 0; st < 4; ++st) {
                    acc[st][tt] = __builtin_amdgcn_mfma_f32_16x16x32_bf16(ah[st], bh, acc[st][tt], 0, 0, 0);
                    acc[st][tt] = __builtin_amdgcn_mfma_f32_16x16x32_bf16(ah[st], bl, acc[st][tt], 0, 0, 0);
                    acc[st][tt] = __builtin_amdgcn_mfma_f32_16x16x32_bf16(al[st], bh, acc[st][tt], 0, 0, 0);
                }
            }
        }

        if (s < 23) STAGE_WRITE(cur ^ 1); // vmcnt wait lands here, after MFMAs
        lgkm_barrier();
    }

    // C/D layout: col = lane&15, row = (lane>>4)*4 + reg  [m89-verified]
    #pragma unroll
    for (int tt = 0; tt < 7; ++tt) {
        const int nt = wc + 4 * tt;
        if (nt < 25) {
            const int n = nt * 16 + fr;
            #pragma unroll
            for (int st = 0; st < 4; ++st) {
                #pragma unroll
                for (int r = 0; r < 4; ++r) {
                    const int m = m0 + rb + st * 16 + (lane >> 4) * 4 + r;
                    xp[(size_t)m * G4 + n] = acc[st][tt][r] + bias_t[tt];
                }
            }
        }
    }
    #undef STAGE_LOAD
    #undef STAGE_WRITE
}

// ---------------------------------------------------------------------------
// Kernel 2: LSTM scan, quarter-split quad cell.
//   KEY CHANGE vs r9: __syncthreads() instead of the inline-asm barrier.
//   The asm "memory" clobber was the register-residency killer (r2 with
//   __syncthreads held 128 VGPRs; r3-r9 with asm barrier capped at 64-88):
//   an opaque clobber makes the 112-float weight array unmaintainable across
//   the barrier, forcing remat/spill (~130 extra instr/step). __syncthreads
//   is a modeled intrinsic - register values survive it.
//   Its vmcnt(0) drain is defused by DEFERRING the hs global store one step
//   (store h_{t-1} at the top of step t -> a full step body to retire).
//   148 KB LDS brake kept (1 block/CU -> relaxed occupancy target).
// ---------------------------------------------------------------------------
__global__ __launch_bounds__(448, 1) void lstm_scan(
    const float* __restrict__ xp,    // (T*B, 400)
    const float* __restrict__ wpack, // (400, 112) packed W_hh
    float* __restrict__ hs)          // (T*B, 100)
{
    const int b   = blockIdx.x;
    const int tid = threadIdx.x;
    const int q   = tid & 3;         // k-quarter
    const int j   = tid >> 2;        // hidden unit 0..111
    const int jc  = (j < H_DIM) ? j : (H_DIM - 1);
    const int row = q * H_DIM + jc;  // xp column for gate q of unit j

    __shared__ __align__(16) float hbuf[2][112];     // quarters at 28-float offsets
    __shared__ float lds_occupancy_brake[37000];     // 148 KB occupancy brake

    // keep the brake alive: opaque (runtime blockIdx) never-true guard
    if (b >= B_DIM) {
        lds_occupancy_brake[tid] = (float)tid;
        hbuf[0][tid & 1] = lds_occupancy_brake[(tid * 7) & 1023];
    }

    // 112 contiguous weights for this lane: 28 float4 loads -> 56 f32x2
    f32x2 w2[56];
    {
        const float* wb = wpack + (size_t)((jc << 2) + q) * 112;
        #pragma unroll
        for (int i = 0; i < 28; ++i) {
            float4 v = *reinterpret_cast<const float4*>(&wb[4 * i]);
            w2[2 * i]     = (f32x2){v.x, v.y};
            w2[2 * i + 1] = (f32x2){v.z, v.w};
        }
    }

    if (tid < 112) { hbuf[0][tid] = 0.f; hbuf[1][tid] = 0.f; }

    const int hpos = (jc / 25) * 28 + (jc % 25);
    const bool writer = (q == 0) && (j < H_DIM);

    // unified activation: act = s*sigm(s*x) - (s-1); s=2 for tanh gate (q==2)
    const float s_act = (q == 2) ? 2.0f : 1.0f;
    const float nsl2  = -s_act * 1.44269504088896f;
    const float nsm1  = 1.0f - s_act;

    float c = 0.f;
    float h_pend = 0.f;              // deferred hs store (written next step)
    const float* xp_ptr = xp + (size_t)b * G4 + row;
    float*       hs_ptr = hs + (size_t)b * H_DIM + jc;
    const size_t xstride = (size_t)B_DIM * G4;

    float xpv = xp_ptr[0];           // step-0 projection
    __syncthreads();

    int p = 0;
    for (int t = 0; t < T_DIM; ++t) {
        // deferred hs store from previous step: a full step to retire
        if (t > 0) {
            if (writer) *hs_ptr = h_pend;
            hs_ptr += B_DIM * H_DIM;
        }
        // prefetch next step's projection (consumed after the barrier)
        float xp_next = 0.f;
        if (t + 1 < T_DIM) xp_next = xp_ptr[xstride];   // uniform branch
        xp_ptr += xstride;

        // packed partial dots over this lane's 28-float (padded) quarter
        f32x2 a0 = {(q == 0) ? xpv : 0.f, 0.f};
        f32x2 a1 = {(q == 1) ? xpv : 0.f, 0.f};
        f32x2 a2 = {(q == 2) ? xpv : 0.f, 0.f};
        f32x2 a3 = {(q == 3) ? xpv : 0.f, 0.f};
        const float* hq = &hbuf[p][28 * q];
        #pragma unroll
        for (int k = 0; k < 7; ++k) {
            float4 hv = *reinterpret_cast<const float4*>(hq + 4 * k);
            f32x2 hlo = {hv.x, hv.y};
            f32x2 hhi = {hv.z, hv.w};
            a0 = __builtin_elementwise_fma(w2[2 * k],          hlo, a0);
            a0 = __builtin_elementwise_fma(w2[2 * k + 1],      hhi, a0);
            a1 = __builtin_elementwise_fma(w2[14 + 2 * k],     hlo, a1);
            a1 = __builtin_elementwise_fma(w2[14 + 2 * k + 1], hhi, a1);
            a2 = __builtin_elementwise_fma(w2[28 + 2 * k],     hlo, a2);
            a2 = __builtin_elementwise_fma(w2[28 + 2 * k + 1], hhi, a2);
            a3 = __builtin_elementwise_fma(w2[42 + 2 * k],     hlo, a3);
            a3 = __builtin_elementwise_fma(w2[42 + 2 * k + 1], hhi, a3);
        }
        float ac0 = a0.x + a0.y;
        float ac1 = a1.x + a1.y;
        float ac2 = a2.x + a2.y;
        float ac3 = a3.x + a3.y;

        // quad butterfly (VALU DPP): full sums in all lanes
        ac0 += qperm<0xB1>(ac0);
        ac1 += qperm<0xB1>(ac1);
        ac2 += qperm<0xB1>(ac2);
        ac3 += qperm<0xB1>(ac3);
        ac0 += qperm<0x4E>(ac0);
        ac1 += qperm<0x4E>(ac1);
        ac2 += qperm<0x4E>(ac2);
        ac3 += qperm<0x4E>(ac3);

        // lane activates only its own gate
        float pre = ac0;
        pre = (q == 1) ? ac1 : pre;
        pre = (q == 2) ? ac2 : pre;
        pre = (q == 3) ? ac3 : pre;
        const float act = fmaf(s_act,
            fast_rcp(1.0f + __builtin_amdgcn_exp2f(nsl2 * pre)), nsm1);

        // quad broadcast of activated gates: slot 0=i, 1=f, 2=g, 3=o
        const float i_ = qperm<0x00>(act);
        const float f_ = qperm<0x55>(act);
        const float g_ = qperm<0xAA>(act);
        const float o_ = qperm<0xFF>(act);

        c = fmaf(f_, c, i_ * g_);
        const float h = o_ * tanh_f(c);

        if (writer) hbuf[p ^ 1][hpos] = h;
        h_pend = h;

        __syncthreads();             // modeled intrinsic: registers survive
        p ^= 1;
        xpv = xp_next;
    }
    if (writer) *hs_ptr = h_pend;    // final step's h
}

// ---------------------------------------------------------------------------
// Kernel 3: FC. out[t,o] = fc_b[o] + hs[t,:] . fcW[o,:]
// ---------------------------------------------------------------------------
__global__ __launch_bounds__(256) void fc_kernel(
    const float* __restrict__ hs,    // (T, 5000)
    const float* __restrict__ fcW,   // (2, 5000)
    const float* __restrict__ fcb,
    float* __restrict__ out)         // (T, 2)
{
    const int t   = blockIdx.x;
    const int tid = threadIdx.x;

    float p0 = 0.f, p1 = 0.f;
    for (int k = tid * 4; k < 5000; k += 1024) {
        const float4 hv = *reinterpret_cast<const float4*>(&hs[(size_t)t * 5000 + k]);
        const float4 w0 = *reinterpret_cast<const float4*>(&fcW[k]);
        const float4 w1 = *reinterpret_cast<const float4*>(&fcW[5000 + k]);
        p0 += hv.x * w0.x + hv.y * w0.y + hv.z * w0.z + hv.w * w0.w;
        p1 += hv.x * w1.x + hv.y * w1.y + hv.z * w1.z + hv.w * w1.w;
    }
    #pragma unroll
    for (int off = 32; off > 0; off >>= 1) {
        p0 += __shfl_xor(p0, off);
        p1 += __shfl_xor(p1, off);
    }
    __shared__ float red[8];
    const int wv = tid >> 6;
    if ((tid & 63) == 0) { red[wv * 2] = p0; red[wv * 2 + 1] = p1; }
    __syncthreads();
    if (tid == 0) {
        out[2 * t]     = fcb[0] + red[0] + red[2] + red[4] + red[6];
        out[2 * t + 1] = fcb[1] + red[1] + red[3] + red[5] + red[7];
    }
}

// ---------------------------------------------------------------------------
extern "C" void kernel_launch(void* const* d_in, const int* in_sizes, int n_in,
                              void* d_out, int out_size, void* d_ws, size_t ws_size,
                              hipStream_t stream) {
    const float* x   = (const float*)d_in[0];
    const float* Wih = (const float*)d_in[1];
    const float* Whh = (const float*)d_in[2];
    const float* bih = (const float*)d_in[3];
    const float* bhh = (const float*)d_in[4];
    const float* fcW = (const float*)d_in[5];
    const float* fcb = (const float*)d_in[6];
    float* out = (float*)d_out;

    // ws layout: xp (163.84 MB) | Whi | Wlo (0.6 MB each) | hs (40.96 MB) | wpack (179 KB)
    char* ws = (char*)d_ws;
    float*          xp    = (float*)ws;
    unsigned short* Whi   = (unsigned short*)(ws + (size_t)M_DIM * G4 * 4);
    unsigned short* Wlo   = Whi + (size_t)G4 * KPAD;
    float*          hs    = (float*)((char*)(Wlo + (size_t)G4 * KPAD));
    float*          wpack = hs + (size_t)M_DIM * H_DIM;

    wconv<<<(G4 * KPAD + 255) / 256, 256, 0, stream>>>(Wih, Whi, Wlo);
    whh_pack<<<(400 * 112 + 255) / 256, 256, 0, stream>>>(Whh, wpack);

    xproj_mfma<<<M_DIM / 128, 512, 0, stream>>>(x, Whi, Wlo, bih, bhh, xp);

    lstm_scan<<<B_DIM, 448, 0, stream>>>(xp, wpack, hs);

    fc_kernel<<<T_DIM, 256, 0, stream>>>(hs, fcW, fcb, out);
}

// Round 12
// 1857.705 us; speedup vs baseline: 1.0388x; 1.0388x over previous
//
#include <hip/hip_runtime.h>

#define T_DIM 2048
#define B_DIM 50
#define F_DIM 750
#define H_DIM 100
#define G4    400             // 4*H
#define M_DIM (T_DIM * B_DIM) // 102400
#define KPAD  768             // F padded to MFMA-friendly K

typedef __attribute__((ext_vector_type(8))) short short8v;  // 8 bf16
typedef __attribute__((ext_vector_type(4))) float f32x4;
typedef __attribute__((ext_vector_type(2))) float f32x2;

__device__ __forceinline__ float fast_rcp(float x) { return __builtin_amdgcn_rcpf(x); }
__device__ __forceinline__ float tanh_f(float x) {
    return 1.0f - 2.0f * fast_rcp(__expf(2.0f * x) + 1.0f);
}

__device__ __forceinline__ unsigned short f2bf_rne(float f) {
    unsigned int u = __float_as_uint(f);
    u = (u + 0x7FFFu + ((u >> 16) & 1u)) >> 16;
    return (unsigned short)u;
}
__device__ __forceinline__ float bf2f(unsigned short h) {
    return __uint_as_float(((unsigned int)h) << 16);
}

template <int CTRL>
__device__ __forceinline__ float qperm(float x) {
    return __int_as_float(__builtin_amdgcn_mov_dpp(__float_as_int(x), CTRL, 0xF, 0xF, false));
}
// lane i <-> lane i^4 (BitMode xor swizzle)
__device__ __forceinline__ float swz_xor4(float x) {
    return __int_as_float(__builtin_amdgcn_ds_swizzle(__float_as_int(x), 0x101F));
}

// asm lgkm-only barrier (r7/r8-proven: fastest passing config)
__device__ __forceinline__ void lgkm_barrier() {
    __builtin_amdgcn_sched_barrier(0);
    asm volatile("s_waitcnt lgkmcnt(0)\ns_barrier" ::: "memory");
    __builtin_amdgcn_sched_barrier(0);
}

// ---------------------------------------------------------------------------
// Kernel 0a: W_ih (400x750 fp32) -> W_hi/W_lo (400x768 bf16, k-padded 0). RNE.
// ---------------------------------------------------------------------------
__global__ __launch_bounds__(256) void wconv(
    const float* __restrict__ W,
    unsigned short* __restrict__ Whi,
    unsigned short* __restrict__ Wlo)
{
    int i = blockIdx.x * 256 + threadIdx.x;
    if (i >= G4 * KPAD) return;
    int g = i / KPAD, k = i - g * KPAD;
    float v = (k < F_DIM) ? W[g * F_DIM + k] : 0.f;
    unsigned short h = f2bf_rne(v);
    Whi[i] = h;
    Wlo[i] = f2bf_rne(v - bf2f(h));
}

// ---------------------------------------------------------------------------
// Kernel 0b: repack W_hh for the OCTET-split scan.
//   Lane (j,q,half) owns 56 contiguous floats: r<50 -> Whh[q*100+j][50*half+r],
//   r>=50 -> 0 pad.  lane_id = (j*4+q)*2 + half.
// ---------------------------------------------------------------------------
__global__ __launch_bounds__(256) void whh_pack(
    const float* __restrict__ Whh,   // (400, 100)
    float* __restrict__ wpack)       // (800 lanes, 56)
{
    int i = blockIdx.x * 256 + threadIdx.x;
    if (i >= 800 * 56) return;
    int lane = i / 56, r = i - lane * 56;
    int half = lane & 1, qj = lane >> 1;
    int q = qj & 3, j = qj >> 2;
    wpack[i] = (r < 50) ? Whh[(size_t)(q * H_DIM + j) * H_DIM + 50 * half + r] : 0.f;
}

// ---------------------------------------------------------------------------
// Kernel 1: xp = x @ W_ih^T + b via bf16 split MFMA.  M-tile 128, 8 waves.
//   (unchanged from rounds 7-11)
// ---------------------------------------------------------------------------
__global__ __launch_bounds__(512, 1) void xproj_mfma(
    const float* __restrict__ x,            // (M, 750)
    const unsigned short* __restrict__ Whi, // (400, 768) bf16
    const unsigned short* __restrict__ Wlo,
    const float* __restrict__ bih,
    const float* __restrict__ bhh,
    float* __restrict__ xp)                 // (M, 400)
{
    const int m0   = blockIdx.x * 128;
    const int tid  = threadIdx.x;
    const int lane = tid & 63;
    const int w    = tid >> 6;            // wave 0..7
    const int rb   = (w >> 2) * 64;       // row block 0 / 64
    const int wc   = w & 3;               // col wave 0..3
    const int fr   = lane & 15;
    const int fk   = (lane >> 4) * 8;

    __shared__ unsigned short Ahi[2][128][40];   // 20 KB
    __shared__ unsigned short Alo[2][128][40];   // 20 KB

    f32x4 acc[4][7];
    #pragma unroll
    for (int s = 0; s < 4; ++s)
        #pragma unroll
        for (int t = 0; t < 7; ++t)
            acc[s][t] = (f32x4){0.f, 0.f, 0.f, 0.f};

    float bias_t[7];
    #pragma unroll
    for (int tt = 0; tt < 7; ++tt) {
        const int nt = wc + 4 * tt;
        if (nt < 25) {
            const int n = nt * 16 + fr;
            bias_t[tt] = bih[n] + bhh[n];
        } else bias_t[tt] = 0.f;
    }

    const int sr = tid >> 2;          // row 0..127
    const int sc = (tid & 3) * 8;     // k-chunk 0/8/16/24
    const float* xrow = x + (size_t)(m0 + sr) * F_DIM;

    float f[8];

    #define STAGE_LOAD(KS)                                                     \
    {                                                                          \
        const int kg = (KS) * 32 + sc;                                         \
        _Pragma("unroll")                                                      \
        for (int i = 0; i < 8; i += 2) {                                       \
            if (kg + i + 1 < F_DIM) {                                          \
                float2 v = *reinterpret_cast<const float2*>(&xrow[kg + i]);    \
                f[i] = v.x; f[i + 1] = v.y;                                    \
            } else {                                                           \
                f[i]     = (kg + i < F_DIM) ? xrow[kg + i] : 0.f;              \
                f[i + 1] = 0.f;                                                \
            }                                                                  \
        }                                                                      \
    }

    #define STAGE_WRITE(NB)                                                    \
    {                                                                          \
        short8v vh, vl;                                                        \
        _Pragma("unroll")                                                      \
        for (int i = 0; i < 8; ++i) {                                          \
            unsigned int u = __float_as_uint(f[i]);                            \
            vh[i] = (short)(u >> 16);                                          \
            float r = f[i] - __uint_as_float(u & 0xffff0000u);                 \
            vl[i] = (short)(__float_as_uint(r) >> 16);                         \
        }                                                                      \
        *reinterpret_cast<short8v*>(&Ahi[NB][sr][sc]) = vh;                    \
        *reinterpret_cast<short8v*>(&Alo[NB][sr][sc]) = vl;                    \
    }

    STAGE_LOAD(0);
    STAGE_WRITE(0);
    lgkm_barrier();

    for (int s = 0; s < 24; ++s) {
        const int cur = s & 1;
        short8v ah[4], al[4];
        #pragma unroll
        for (int st = 0; st < 4; ++st) {
            ah[st] = *reinterpret_cast<const short8v*>(&Ahi[cur][rb + st * 16 + fr][fk]);
            al[st] = *reinterpret_cast<const short8v*>(&Alo[cur][rb + st * 16 + fr][fk]);
        }

        if (s < 23) STAGE_LOAD(s + 1);    // issue loads early; consume after MFMA

        const int kb = s * 32 + fk;
        #pragma unroll
        for (int tt = 0; tt < 7; ++tt) {
            const int nt = wc + 4 * tt;
            if (nt < 25) {
                const int n = nt * 16 + fr;
                const short8v bh = *reinterpret_cast<const short8v*>(&Whi[n * KPAD + kb]);
                const short8v bl = *reinterpret_cast<const short8v*>(&Wlo[n * KPAD + kb]);
                #pragma unroll
                for (int st = 0; st < 4; ++st) {
                    acc[st][tt] = __builtin_amdgcn_mfma_f32_16x16x32_bf16(ah[st], bh, acc[st][tt], 0, 0, 0);
                    acc[st][tt] = __builtin_amdgcn_mfma_f32_16x16x32_bf16(ah[st], bl, acc[st][tt], 0, 0, 0);
                    acc[st][tt] = __builtin_amdgcn_mfma_f32_16x16x32_bf16(al[st], bh, acc[st][tt], 0, 0, 0);
                }
            }
        }

        if (s < 23) STAGE_WRITE(cur ^ 1); // vmcnt wait lands here, after MFMAs
        lgkm_barrier();
    }

    // C/D layout: col = lane&15, row = (lane>>4)*4 + reg  [m89-verified]
    #pragma unroll
    for (int tt = 0; tt < 7; ++tt) {
        const int nt = wc + 4 * tt;
        if (nt < 25) {
            const int n = nt * 16 + fr;
            #pragma unroll
            for (int st = 0; st < 4; ++st) {
                #pragma unroll
                for (int r = 0; r < 4; ++r) {
                    const int m = m0 + rb + st * 16 + (lane >> 4) * 4 + r;
                    xp[(size_t)m * G4 + n] = acc[st][tt][r] + bias_t[tt];
                }
            }
        }
    }
    #undef STAGE_LOAD
    #undef STAGE_WRITE
}

// ---------------------------------------------------------------------------
// Kernel 2: LSTM scan, OCTET-split cell (8 lanes per hidden unit).
//   Lane (j, q, half): gate q, k-half [50*half, 50*half+50). 56 weights/lane
//   (14 float4) -> fits the ~88-VGPR grant. BUGFIX vs r11: xpv is seeded
//   ONLY in the half==0 lane; both halves loading xp[q*100+j] and both
//   seeding it double-counted it after the xor-4 half-sum (absmax 1.86).
// ---------------------------------------------------------------------------
__global__ __launch_bounds__(832, 1) void lstm_scan(
    const float* __restrict__ xp,    // (T*B, 400)
    const float* __restrict__ wpack, // (800 lanes, 56) packed W_hh
    float* __restrict__ hs)          // (T*B, 100)
{
    const int b    = blockIdx.x;
    const int tid  = threadIdx.x;
    const int oct  = tid & 7;        // (half<<2) | q
    const int q    = oct & 3;        // gate 0=i 1=f 2=g 3=o
    const int half = oct >> 2;       // k-half
    const int j    = tid >> 3;       // hidden unit 0..103
    const int jc   = (j < H_DIM) ? j : (H_DIM - 1);
    const int row  = q * H_DIM + jc; // xp column for gate q of unit j

    // hbuf[p]: h[k] at slot k (k<50) or 56+(k-50); pads [50..56)/[106..112) = 0
    __shared__ __align__(16) float hbuf[2][112];
    __shared__ float lds_occupancy_brake[37000];     // 148 KB occupancy brake

    // keep the brake alive: opaque (runtime blockIdx) never-true guard
    if (b >= B_DIM) {
        lds_occupancy_brake[tid] = (float)tid;
        hbuf[0][tid & 1] = lds_occupancy_brake[(tid * 7) & 1023];
    }

    // 56 contiguous weights for this lane: 14 float4 loads -> 28 f32x2
    f32x2 w2[28];
    {
        const float* wb = wpack + (size_t)(((jc << 2) + q) * 2 + half) * 56;
        #pragma unroll
        for (int i = 0; i < 14; ++i) {
            float4 v = *reinterpret_cast<const float4*>(&wb[4 * i]);
            w2[2 * i]     = (f32x2){v.x, v.y};
            w2[2 * i + 1] = (f32x2){v.z, v.w};
        }
    }

    if (tid < 112) { hbuf[0][tid] = 0.f; hbuf[1][tid] = 0.f; }

    const int hslot = (jc < 50) ? jc : (56 + jc - 50);
    const bool writer = (oct == 0) && (j < H_DIM);

    // unified activation: act = s*sigm(s*x) - (s-1); s=2 for tanh gate (q==2)
    const float s_act = (q == 2) ? 2.0f : 1.0f;
    const float nsl2  = -s_act * 1.44269504088896f;
    const float nsm1  = 1.0f - s_act;

    float c = 0.f;
    const float* xp_ptr = xp + (size_t)b * G4 + row;
    float*       hs_ptr = hs + (size_t)b * H_DIM + jc;
    const size_t xstride = (size_t)B_DIM * G4;

    float xpv   = xp_ptr[0];
    float xp_n1 = xp_ptr[xstride];
    __syncthreads();

    int p = 0;
    for (int t = 0; t < T_DIM; ++t) {
        float xp_n2 = 0.f;
        if (t + 2 < T_DIM) xp_n2 = xp_ptr[2 * xstride];   // uniform branch
        xp_ptr += xstride;

        // partial dot over this lane's k-half: 14 b128 reads, 28 pk_fma.
        // xpv seeded ONLY in half==0 (the xor-4 sum adds both halves).
        f32x2 a0 = {(half == 0) ? xpv : 0.f, 0.f};
        f32x2 a1 = {0.f, 0.f};
        const float* hq = &hbuf[p][half * 56];
        #pragma unroll
        for (int k = 0; k < 7; ++k) {
            float4 hv0 = *reinterpret_cast<const float4*>(hq + 8 * k);
            float4 hv1 = *reinterpret_cast<const float4*>(hq + 8 * k + 4);
            a0 = __builtin_elementwise_fma(w2[4 * k],     (f32x2){hv0.x, hv0.y}, a0);
            a0 = __builtin_elementwise_fma(w2[4 * k + 1], (f32x2){hv0.z, hv0.w}, a0);
            a1 = __builtin_elementwise_fma(w2[4 * k + 2], (f32x2){hv1.x, hv1.y}, a1);
            a1 = __builtin_elementwise_fma(w2[4 * k + 3], (f32x2){hv1.z, hv1.w}, a1);
        }
        float ac = (a0.x + a0.y) + (a1.x + a1.y);

        // sum the two k-halves: lane (q,half) <-> (q,half^1)
        ac += swz_xor4(ac);

        // lane activates only its own gate
        const float act = fmaf(s_act,
            fast_rcp(1.0f + __builtin_amdgcn_exp2f(nsl2 * ac)), nsm1);

        // quad broadcast of activated gates within each aligned quad
        const float i_ = qperm<0x00>(act);
        const float f_ = qperm<0x55>(act);
        const float g_ = qperm<0xAA>(act);
        const float o_ = qperm<0xFF>(act);

        c = fmaf(f_, c, i_ * g_);
        const float h = o_ * tanh_f(c);

        if (writer) {
            hbuf[p ^ 1][hslot] = h;
            *hs_ptr = h;
        }
        hs_ptr += B_DIM * H_DIM;
        lgkm_barrier();
        p ^= 1;
        xpv   = xp_n1;
        xp_n1 = xp_n2;
    }
}

// ---------------------------------------------------------------------------
// Kernel 3: FC. out[t,o] = fc_b[o] + hs[t,:] . fcW[o,:]
// ---------------------------------------------------------------------------
__global__ __launch_bounds__(256) void fc_kernel(
    const float* __restrict__ hs,    // (T, 5000)
    const float* __restrict__ fcW,   // (2, 5000)
    const float* __restrict__ fcb,
    float* __restrict__ out)         // (T, 2)
{
    const int t   = blockIdx.x;
    const int tid = threadIdx.x;

    float p0 = 0.f, p1 = 0.f;
    for (int k = tid * 4; k < 5000; k += 1024) {
        const float4 hv = *reinterpret_cast<const float4*>(&hs[(size_t)t * 5000 + k]);
        const float4 w0 = *reinterpret_cast<const float4*>(&fcW[k]);
        const float4 w1 = *reinterpret_cast<const float4*>(&fcW[5000 + k]);
        p0 += hv.x * w0.x + hv.y * w0.y + hv.z * w0.z + hv.w * w0.w;
        p1 += hv.x * w1.x + hv.y * w1.y + hv.z * w1.z + hv.w * w1.w;
    }
    #pragma unroll
    for (int off = 32; off > 0; off >>= 1) {
        p0 += __shfl_xor(p0, off);
        p1 += __shfl_xor(p1, off);
    }
    __shared__ float red[8];
    const int wv = tid >> 6;
    if ((tid & 63) == 0) { red[wv * 2] = p0; red[wv * 2 + 1] = p1; }
    __syncthreads();
    if (tid == 0) {
        out[2 * t]     = fcb[0] + red[0] + red[2] + red[4] + red[6];
        out[2 * t + 1] = fcb[1] + red[1] + red[3] + red[5] + red[7];
    }
}

// ---------------------------------------------------------------------------
extern "C" void kernel_launch(void* const* d_in, const int* in_sizes, int n_in,
                              void* d_out, int out_size, void* d_ws, size_t ws_size,
                              hipStream_t stream) {
    const float* x   = (const float*)d_in[0];
    const float* Wih = (const float*)d_in[1];
    const float* Whh = (const float*)d_in[2];
    const float* bih = (const float*)d_in[3];
    const float* bhh = (const float*)d_in[4];
    const float* fcW = (const float*)d_in[5];
    const float* fcb = (const float*)d_in[6];
    float* out = (float*)d_out;

    // ws layout: xp (163.84 MB) | Whi | Wlo (0.6 MB each) | hs (40.96 MB) | wpack (179 KB)
    char* ws = (char*)d_ws;
    float*          xp    = (float*)ws;
    unsigned short* Whi   = (unsigned short*)(ws + (size_t)M_DIM * G4 * 4);
    unsigned short* Wlo   = Whi + (size_t)G4 * KPAD;
    float*          hs    = (float*)((char*)(Wlo + (size_t)G4 * KPAD));
    float*          wpack = hs + (size_t)M_DIM * H_DIM;

    wconv<<<(G4 * KPAD + 255) / 256, 256, 0, stream>>>(Wih, Whi, Wlo);
    whh_pack<<<(800 * 56 + 255) / 256, 256, 0, stream>>>(Whh, wpack);

    xproj_mfma<<<M_DIM / 128, 512, 0, stream>>>(x, Whi, Wlo, bih, bhh, xp);

    lstm_scan<<<B_DIM, 832, 0, stream>>>(xp, wpack, hs);

    fc_kernel<<<T_DIM, 256, 0, stream>>>(hs, fcW, fcb, out);
}